// Round 7
// baseline (636.106 us; speedup 1.0000x reference)
//
#include <hip/hip_runtime.h>
#include <hip/hip_bf16.h>
#include <math.h>

#define NN 50000
#define DD 128
#define EE 800000

static constexpr float BN_EPS = 1e-3f;

typedef __attribute__((ext_vector_type(8))) short bf16x8;
typedef __attribute__((ext_vector_type(4))) float f32x4;

#define MFMA16(a, b, c) __builtin_amdgcn_mfma_f32_16x16x32_bf16((a), (b), (c), 0, 0, 0)

// fast exact-grade GELU: Abramowitz-Stegun 7.1.26 erf (abs err 1.5e-7)
__device__ __forceinline__ float gelu_f(float x) {
    float ax = fabsf(x) * 0.7071067811865475f;
    float t = __builtin_amdgcn_rcpf(fmaf(0.3275911f, ax, 1.0f));
    float p = t * fmaf(t, fmaf(t, fmaf(t, fmaf(t, 1.061405429f, -1.453152027f),
                                       1.421413741f), -0.284496736f), 0.254829592f);
    float e = __expf(-ax * ax);
    float er = fmaf(-p, e, 1.0f);        // erf(|x|/sqrt2) for ax>=0
    float s = copysignf(er, x);
    return 0.5f * x * (1.0f + s);
}

__device__ __forceinline__ ushort f2bf_rn(float f) {
    uint u = __float_as_uint(f);
    return (ushort)((u + 0x7FFFu + ((u >> 16) & 1u)) >> 16);
}
__device__ __forceinline__ float bf2f(ushort h) {
    return __uint_as_float(((uint)h) << 16);
}

// packed pair f32->bf16 RNE (compiler emits v_cvt_pk_bf16_f32)
__device__ __forceinline__ uint pk2(float a, float b) {
    __hip_bfloat162 t = __float22bfloat162_rn(make_float2(a, b));
    uint r;
    __builtin_memcpy(&r, &t, 4);
    return r;
}

// split f32x8 -> bf16 hi + bf16 lo fragments (f ~= hi + lo, |resid| ~ 2^-17|f|)
__device__ __forceinline__ void cvt_hilo(float4 x0, float4 x1, bf16x8& h, bf16x8& l) {
    float f[8] = {x0.x, x0.y, x0.z, x0.w, x1.x, x1.y, x1.z, x1.w};
    union U { uint u[4]; bf16x8 v; } uh, ul;
    #pragma unroll
    for (int j = 0; j < 4; ++j) {
        uint p = pk2(f[2 * j], f[2 * j + 1]);
        uh.u[j] = p;
        float h0 = __uint_as_float(p << 16);
        float h1 = __uint_as_float(p & 0xFFFF0000u);
        ul.u[j] = pk2(f[2 * j] - h0, f[2 * j + 1] - h1);
    }
    h = uh.v;
    l = ul.v;
}

// ---------------- fold + pack kernels ----------------
// Fold BN scale into W and pack into MFMA B-fragment order, split bf16 hi/lo.
// Fragment layout for 16x16x32: lane ln holds col = c*16+(ln&15), k = st*32+(ln>>4)*8+j.
// Element (k,col) of folded W -> plane offset ((c*(K/32)+st)*64+ln)*8+j.
__global__ void pack_w(const float* __restrict__ W, const float* __restrict__ g,
                       const float* __restrict__ v, ushort* __restrict__ hi,
                       ushort* __restrict__ lo, int K) {
    int idx = blockIdx.x * 256 + threadIdx.x;
    if (idx >= K * DD) return;
    int k = idx >> 7, col = idx & 127;
    float s = g[k] * rsqrtf(v[k] + BN_EPS);
    float f = s * W[idx];
    int S = K >> 5;
    int st = k >> 5, gq = (k >> 3) & 3, j = k & 7;
    int c = col >> 4, ln = (gq << 4) | (col & 15);
    int o = ((c * S + st) * 64 + ln) * 8 + j;
    ushort hb = f2bf_rn(f);
    hi[o] = hb;
    lo[o] = f2bf_rn(f - bf2f(hb));
}

// b'[j] = bias[j] + sum_k (b[k]-m[k]*s[k]) * W[k][j]   (kept f32, added post-MFMA)
__global__ void fold_b(const float* __restrict__ W, const float* __restrict__ g,
                       const float* __restrict__ bb, const float* __restrict__ m,
                       const float* __restrict__ v, const float* __restrict__ bias,
                       float* __restrict__ bf, int K) {
    int j = threadIdx.x;  // 128 threads
    float acc = 0.f;
    for (int k = 0; k < K; ++k) {
        float s = g[k] * rsqrtf(v[k] + BN_EPS);
        float t = bb[k] - m[k] * s;
        acc = fmaf(t, W[k * DD + j], acc);
    }
    bf[j] = bias[j] + acc;
}

// Y LDS row stride in ushorts: 136 (272 B) -> read banks 4*lr mod 32 (2-way, free)
#define YLD 136

// ---------------- edge kernel: gather -> MFMA FFN(2 layers) -> *ew -> atomic scatter ----
// 128 edges/block, 8 waves x 16 rows. Y handoff stored as bf16 (hi only) -> LDS 34816 B
// -> 4 blocks/CU. Layer-2 A-fragments read directly from LDS (no cvt), 2 MFMAs (B hi/lo).
// Per-wave Y slices -> no __syncthreads.
__global__ __launch_bounds__(512, 4) void edge_kernel(
    const float* __restrict__ reps, const int* __restrict__ edges,
    const float* __restrict__ ew,
    const ushort* __restrict__ W1h, const ushort* __restrict__ W1l, const float* __restrict__ B1,
    const ushort* __restrict__ W2h, const ushort* __restrict__ W2l, const float* __restrict__ B2,
    float* __restrict__ agg)
{
    __shared__ ushort Yh[128 * YLD];
    const int t = threadIdx.x;
    const int w = t >> 6, l = t & 63, lg = l >> 4, lr = l & 15;
    const int e0 = blockIdx.x * 128;
    const int erow = e0 + w * 16;

    float b1v[8], b2v[8];
    #pragma unroll
    for (int c = 0; c < 8; ++c) { b1v[c] = B1[c * 16 + lr]; b2v[c] = B2[c * 16 + lr]; }

    const int nb = edges[EE + erow + lr];  // neighbour (edges row 1)
    const float* src = reps + (size_t)nb * DD;

    // prefetch edge weight + dest node for the scatter (hide latency under MFMA)
    float ewv[4];
    int nd[4];
    #pragma unroll
    for (int i = 0; i < 4; ++i) {
        int e = erow + lg * 4 + i;
        ewv[i] = ew[e];
        nd[i] = edges[e];  // dest node (edges row 0)
    }

    f32x4 acc[8];
    #pragma unroll
    for (int c = 0; c < 8; ++c) acc[c] = (f32x4)(0.f);

    // ---- layer 1 (A hi+lo, 3 MFMAs) ----
    #pragma unroll
    for (int s = 0; s < 4; ++s) {
        float4 x0 = *reinterpret_cast<const float4*>(src + s * 32 + lg * 8);
        float4 x1 = *reinterpret_cast<const float4*>(src + s * 32 + lg * 8 + 4);
        bf16x8 ah, al;
        cvt_hilo(x0, x1, ah, al);
        #pragma unroll
        for (int c = 0; c < 8; ++c) {
            bf16x8 bh = *reinterpret_cast<const bf16x8*>(W1h + (size_t)((c * 4 + s) * 64 + l) * 8);
            bf16x8 bl = *reinterpret_cast<const bf16x8*>(W1l + (size_t)((c * 4 + s) * 64 + l) * 8);
            acc[c] = MFMA16(al, bh, acc[c]);
            acc[c] = MFMA16(ah, bl, acc[c]);
            acc[c] = MFMA16(ah, bh, acc[c]);
        }
    }
    // bias + GELU -> Yh bf16 (D layout: row=w*16+lg*4+i, col=c*16+lr); own-wave rows only
    #pragma unroll
    for (int c = 0; c < 8; ++c) {
        #pragma unroll
        for (int i = 0; i < 4; ++i) {
            float yv = gelu_f(acc[c][i] + b1v[c]);
            Yh[(w * 16 + lg * 4 + i) * YLD + c * 16 + lr] = f2bf_rn(yv);
        }
    }

    // ---- layer 2 (A = bf16 Y read straight from LDS; B hi/lo -> 2 MFMAs) ----
    #pragma unroll
    for (int c = 0; c < 8; ++c) acc[c] = (f32x4)(0.f);
    const ushort* yr = Yh + (w * 16 + lr) * YLD;
    #pragma unroll
    for (int s = 0; s < 4; ++s) {
        bf16x8 ah = *reinterpret_cast<const bf16x8*>(yr + s * 32 + lg * 8);
        #pragma unroll
        for (int c = 0; c < 8; ++c) {
            bf16x8 bh = *reinterpret_cast<const bf16x8*>(W2h + (size_t)((c * 4 + s) * 64 + l) * 8);
            bf16x8 bl = *reinterpret_cast<const bf16x8*>(W2l + (size_t)((c * 4 + s) * 64 + l) * 8);
            acc[c] = MFMA16(ah, bl, acc[c]);
            acc[c] = MFMA16(ah, bh, acc[c]);
        }
    }

    // ---- bias + GELU + *ew + atomic scatter ----
    #pragma unroll
    for (int i = 0; i < 4; ++i) {
        float* dst = agg + (size_t)nd[i] * DD + lr;
        #pragma unroll
        for (int c = 0; c < 8; ++c) {
            float vv = gelu_f(acc[c][i] + b2v[c]) * ewv[i];
            atomicAdd(dst + c * 16, vv);
        }
    }
}

// ---------------- node kernel: concat -> MFMA FFN(2 layers) -> L2 normalize ----
// 64 nodes/block, 4 waves x 16 rows. Y bf16 in LDS (17408 B). No __syncthreads.
__global__ __launch_bounds__(256, 4) void node_kernel(
    const float* __restrict__ reps, const float* __restrict__ agg,
    const ushort* __restrict__ U1h, const ushort* __restrict__ U1l, const float* __restrict__ C1,
    const ushort* __restrict__ U2h, const ushort* __restrict__ U2l, const float* __restrict__ C2,
    float* __restrict__ out)
{
    __shared__ ushort Yh[64 * YLD];
    const int t = threadIdx.x;
    const int w = t >> 6, l = t & 63, lg = l >> 4, lr = l & 15;
    const int n0 = blockIdx.x * 64;
    int n = n0 + w * 16 + lr;
    int nc = n < NN ? n : NN - 1;  // clamp tail loads; stores guarded

    float c1v[8], c2v[8];
    #pragma unroll
    for (int c = 0; c < 8; ++c) { c1v[c] = C1[c * 16 + lr]; c2v[c] = C2[c * 16 + lr]; }

    f32x4 acc[8];
    #pragma unroll
    for (int c = 0; c < 8; ++c) acc[c] = (f32x4)(0.f);

    // ---- update layer 1: K=256, concat [reps | agg], A hi+lo ----
    #pragma unroll
    for (int s = 0; s < 8; ++s) {
        int kb = s * 32 + lg * 8;
        const float* sp = (kb < 128) ? (reps + (size_t)nc * DD + kb)
                                     : (agg + (size_t)nc * DD + (kb - 128));
        float4 x0 = *reinterpret_cast<const float4*>(sp);
        float4 x1 = *reinterpret_cast<const float4*>(sp + 4);
        bf16x8 ah, al;
        cvt_hilo(x0, x1, ah, al);
        #pragma unroll
        for (int c = 0; c < 8; ++c) {
            bf16x8 bh = *reinterpret_cast<const bf16x8*>(U1h + (size_t)((c * 8 + s) * 64 + l) * 8);
            bf16x8 bl = *reinterpret_cast<const bf16x8*>(U1l + (size_t)((c * 8 + s) * 64 + l) * 8);
            acc[c] = MFMA16(al, bh, acc[c]);
            acc[c] = MFMA16(ah, bl, acc[c]);
            acc[c] = MFMA16(ah, bh, acc[c]);
        }
    }
    #pragma unroll
    for (int c = 0; c < 8; ++c) {
        #pragma unroll
        for (int i = 0; i < 4; ++i) {
            float yv = gelu_f(acc[c][i] + c1v[c]);
            Yh[(w * 16 + lg * 4 + i) * YLD + c * 16 + lr] = f2bf_rn(yv);
        }
    }

    // ---- update layer 2: K=128, A = bf16 Y from LDS, 2 MFMAs ----
    #pragma unroll
    for (int c = 0; c < 8; ++c) acc[c] = (f32x4)(0.f);
    const ushort* yr = Yh + (w * 16 + lr) * YLD;
    #pragma unroll
    for (int s = 0; s < 4; ++s) {
        bf16x8 ah = *reinterpret_cast<const bf16x8*>(yr + s * 32 + lg * 8);
        #pragma unroll
        for (int c = 0; c < 8; ++c) {
            bf16x8 bh = *reinterpret_cast<const bf16x8*>(U2h + (size_t)((c * 4 + s) * 64 + l) * 8);
            bf16x8 bl = *reinterpret_cast<const bf16x8*>(U2l + (size_t)((c * 4 + s) * 64 + l) * 8);
            acc[c] = MFMA16(ah, bl, acc[c]);
            acc[c] = MFMA16(ah, bh, acc[c]);
        }
    }

    // ---- bias + GELU + L2 normalize + store ----
    float ssq[4] = {0.f, 0.f, 0.f, 0.f};
    #pragma unroll
    for (int c = 0; c < 8; ++c) {
        #pragma unroll
        for (int i = 0; i < 4; ++i) {
            float vv = gelu_f(acc[c][i] + c2v[c]);
            acc[c][i] = vv;
            ssq[i] = fmaf(vv, vv, ssq[i]);
        }
    }
    // row r = w*16 + lg*4 + i lives in the 16 lanes of group lg, reg i
    #pragma unroll
    for (int i = 0; i < 4; ++i) {
        #pragma unroll
        for (int msk = 1; msk < 16; msk <<= 1) ssq[i] += __shfl_xor(ssq[i], msk);
        ssq[i] = rsqrtf(fmaxf(ssq[i], 1e-12f));
    }
    const int nrow = n0 + w * 16 + lg * 4;
    #pragma unroll
    for (int i = 0; i < 4; ++i) {
        if (nrow + i < NN) {
            #pragma unroll
            for (int c = 0; c < 8; ++c)
                out[(size_t)(nrow + i) * DD + c * 16 + lr] = acc[c][i] * ssq[i];
        }
    }
}

// ---------------- launch ----------------
extern "C" void kernel_launch(void* const* d_in, const int* in_sizes, int n_in,
                              void* d_out, int out_size, void* d_ws, size_t ws_size,
                              hipStream_t stream)
{
    const float* reps = (const float*)d_in[0];
    const int*   edges = (const int*)d_in[1];
    const float* ew   = (const float*)d_in[2];
    const float* bn1g = (const float*)d_in[3];
    const float* bn1b = (const float*)d_in[4];
    const float* bn1m = (const float*)d_in[5];
    const float* bn1v = (const float*)d_in[6];
    const float* w1   = (const float*)d_in[7];
    const float* b1   = (const float*)d_in[8];
    const float* bn2g = (const float*)d_in[9];
    const float* bn2b = (const float*)d_in[10];
    const float* bn2m = (const float*)d_in[11];
    const float* bn2v = (const float*)d_in[12];
    const float* w2   = (const float*)d_in[13];
    const float* b2   = (const float*)d_in[14];
    const float* ubn1g = (const float*)d_in[15];
    const float* ubn1b = (const float*)d_in[16];
    const float* ubn1m = (const float*)d_in[17];
    const float* ubn1v = (const float*)d_in[18];
    const float* u1    = (const float*)d_in[19];
    const float* ub1   = (const float*)d_in[20];
    const float* ubn2g = (const float*)d_in[21];
    const float* ubn2b = (const float*)d_in[22];
    const float* ubn2m = (const float*)d_in[23];
    const float* ubn2v = (const float*)d_in[24];
    const float* u2    = (const float*)d_in[25];
    const float* ub2   = (const float*)d_in[26];

    // workspace layout
    float* ws  = (float*)d_ws;
    float* agg = ws;                       // 6,400,000 f32
    float* B1f = ws + 6400000;             // 128
    float* B2f = B1f + 128;
    float* C1f = B2f + 128;
    float* C2f = C1f + 128;
    ushort* up  = (ushort*)(C2f + 128);    // byte offset 25,602,048 (16B aligned)
    ushort* W1h = up;                      // 16384 each
    ushort* W1l = W1h + 16384;
    ushort* W2h = W1l + 16384;
    ushort* W2l = W2h + 16384;
    ushort* U1h = W2l + 16384;             // 32768 each
    ushort* U1l = U1h + 32768;
    ushort* U2h = U1l + 32768;             // 16384 each
    ushort* U2l = U2h + 16384;
    if (ws_size < (size_t)6400512 * 4 + (size_t)163840 * 2) return;

    pack_w<<<64,  256, 0, stream>>>(w1, bn1g, bn1v, W1h, W1l, 128);
    fold_b<<<1,   128, 0, stream>>>(w1, bn1g, bn1b, bn1m, bn1v, b1, B1f, 128);
    pack_w<<<64,  256, 0, stream>>>(w2, bn2g, bn2v, W2h, W2l, 128);
    fold_b<<<1,   128, 0, stream>>>(w2, bn2g, bn2b, bn2m, bn2v, b2, B2f, 128);
    pack_w<<<128, 256, 0, stream>>>(u1, ubn1g, ubn1v, U1h, U1l, 256);
    fold_b<<<1,   128, 0, stream>>>(u1, ubn1g, ubn1b, ubn1m, ubn1v, ub1, C1f, 256);
    pack_w<<<64,  256, 0, stream>>>(u2, ubn2g, ubn2v, U2h, U2l, 128);
    fold_b<<<1,   128, 0, stream>>>(u2, ubn2g, ubn2b, ubn2m, ubn2v, ub2, C2f, 128);

    (void)hipMemsetAsync(agg, 0, (size_t)NN * DD * sizeof(float), stream);

    edge_kernel<<<EE / 128, 512, 0, stream>>>(reps, edges, ew, W1h, W1l, B1f,
                                              W2h, W2l, B2f, agg);
    node_kernel<<<(NN + 63) / 64, 256, 0, stream>>>(reps, agg, U1h, U1l, C1f,
                                                    U2h, U2l, C2f, (float*)d_out);
}